// Round 4
// baseline (166.230 us; speedup 1.0000x reference)
//
#include <hip/hip_runtime.h>
#include <hip/hip_bf16.h>
#include <math.h>

// Problem constants (fixed by reference setup_inputs)
constexpr int NROWS = 8192;   // B
constexpr int HDIM  = 256;    // H (= K of the GEMM)
constexpr int N2    = 16384;  // 2*B rows of Z
constexpr int TM    = 256;    // tile M = tile N (256x256, 8 waves of 128x64)
constexpr int KSUB  = 32;     // K columns per LDS piece (same layout as R9 chunk)
constexpr int PIECE = TM * KSUB;      // 8192 elems = 16 KB per piece
constexpr int NTILE = N2 / TM;        // 64 tile-rows
constexpr int NBLK  = NTILE * (NTILE + 1) / 2;  // 2080 upper-tri tiles

// sqrt(2 * log2(e)): Z pre-scaled so Zs_i.Zs_j = 2*log2(e)*cos and
// exp2(acc) == exp(sim/tau), tau = 0.5
constexpr float PRESCALE = 1.69864357f;

typedef __attribute__((ext_vector_type(4))) float floatx4;
typedef __attribute__((ext_vector_type(8))) short shortx8; // 8 bf16 = 4 VGPRs

__device__ __forceinline__ void async_copy16(const void* gptr, void* lptr) {
    __builtin_amdgcn_global_load_lds(
        (const __attribute__((address_space(1))) unsigned int*)gptr,
        (__attribute__((address_space(3))) unsigned int*)lptr, 16, 0, 0);
}

// s_waitcnt immediates (gfx9: vm[3:0], exp[6:4], lgkm[11:8], vm-hi[15:14])
#define GATE(IMM)    __builtin_amdgcn_s_waitcnt(IMM)
#define NOGATE       ((void)0)
#define NOSTAGE      ((void)0)
#define MEMFENCE()   __asm__ __volatile__("" ::: "memory")
#define RAW_BARRIER() do { MEMFENCE(); __builtin_amdgcn_s_barrier(); MEMFENCE(); } while (0)

// DPP row_shl add: VALU pipe, not DS (R9: -18us vs ds_bpermute shuffles).
#define DPP_ROW_SHL_ADD(v, CTRL) do {                                        \
    union { float f; int i; } _u, _r; _u.f = (v);                            \
    _r.i = __builtin_amdgcn_update_dpp(0, _u.i, (CTRL), 0xF, 0xF, true);     \
    (v) += _r.f; } while (0)

// ---------------------------------------------------------------------------
// Kernel 1: wave-per-row L2-normalize -> bf16 Z (pre-scaled); pos = cos(x,y).
// Also zeroes rowsum and out (stream-ordered before consumers).
// ---------------------------------------------------------------------------
__global__ __launch_bounds__(256) void normalize_kernel(
    const float* __restrict__ x, const float* __restrict__ y,
    __hip_bfloat16* __restrict__ Z, float* __restrict__ pos,
    float* __restrict__ rowsum, float* __restrict__ out)
{
    const int wave = threadIdx.x >> 6, lane = threadIdx.x & 63;
    const int row  = blockIdx.x * 4 + wave;           // grid 2048 -> 8192 rows

    const float4 xv = ((const float4*)x)[row * 64 + lane];
    const float4 yv = ((const float4*)y)[row * 64 + lane];

    float sx  = xv.x*xv.x + xv.y*xv.y + xv.z*xv.z + xv.w*xv.w;
    float sy  = yv.x*yv.x + yv.y*yv.y + yv.z*yv.z + yv.w*yv.w;
    float sxy = xv.x*yv.x + xv.y*yv.y + xv.z*yv.z + xv.w*yv.w;
    #pragma unroll
    for (int m = 1; m < 64; m <<= 1) {
        sx  += __shfl_xor(sx,  m);
        sy  += __shfl_xor(sy,  m);
        sxy += __shfl_xor(sxy, m);
    }
    const float rxn = rsqrtf(sx), ryn = rsqrtf(sy);
    const float rx = rxn * PRESCALE, ry = ryn * PRESCALE;

    union { ushort4 u; __hip_bfloat16 h[4]; } zx, zy;
    zx.h[0] = __float2bfloat16(xv.x * rx); zx.h[1] = __float2bfloat16(xv.y * rx);
    zx.h[2] = __float2bfloat16(xv.z * rx); zx.h[3] = __float2bfloat16(xv.w * rx);
    zy.h[0] = __float2bfloat16(yv.x * ry); zy.h[1] = __float2bfloat16(yv.y * ry);
    zy.h[2] = __float2bfloat16(yv.z * ry); zy.h[3] = __float2bfloat16(yv.w * ry);
    ((ushort4*)Z)[row * 64 + lane]             = zx.u;
    ((ushort4*)Z)[(row + NROWS) * 64 + lane]   = zy.u;

    if (lane == 0) {
        const float p = sxy * rxn * ryn;
        pos[row]         = p;
        pos[row + NROWS] = p;
    }
    const int gt = blockIdx.x * 256 + threadIdx.x;
    if (gt < N2) rowsum[gt] = 0.f;
    if (gt == 0) out[0] = 0.f;
}

// ---------------------------------------------------------------------------
// Kernel 2: upper-triangle tiled Z·Z^T, fused exp2 + row/col sums.
// R13: R11's 16-phase counted-vmcnt schedule with the per-phase
// sched_barrier(0) pins REMOVED (m141: order-pinning defeats the compiler
// scheduler, -40%; m201's template has no pins). Everything else is the
// R11 source that passed (absmax 0.0): same phase bodies, same piece/slot
// rotation, same gate timeline.
//   K = 4 K-tiles of 64 = 8 "pieces" [256 rows][32 cols] (A-ks0/A-ks1/
//   B-ks0/B-ks1 x 2 bufs, 16KB each; R9 chunk layout -> staging XOR
//   swizzle and fragment sw swizzle carry over verbatim, 0 conflicts).
// Phase (kt, p) for p = (ks, fm-half):
//   pre-region: ds_read 4x af (+4x bfr at fm-half 0); issue 1 piece stage
//               (into the slot freed one phase earlier); [counted vmcnt];
//   leading barrier; setprio(1); 16 MFMA; setprio(0); trailing barrier.
// WAR proof: a wave passing a trailing barrier has that phase's ds_reads
// retired (compiler lgkm gates before its MFMAs + in-order DS retirement),
// so the next phase's stage into the freed slot cannot clobber live reads.
// RAW proof: counted vmcnt gates (audited piece-retirement ledger: each
// gate retires exactly the pieces consumed in the next two phases, for ALL
// waves once the following barrier collectivizes). Gates keep 5 pieces
// (80KB) in flight -> issue-to-wait lead >= 5 phases (T4, never drain to 0
// until the tail).
// ---------------------------------------------------------------------------
__global__ __launch_bounds__(512, 2) void simgemm_kernel(
    const __hip_bfloat16* __restrict__ Z, float* __restrict__ rowsum)
{
    // ---- XCD-local block -> (bi,bj) mapping (bijection onto upper tri) ----
    // 2080 = 8 XCDs x 260; per XCD: 36 diag-group tiles + 7 off-diag halves(4x8)
    const int b = blockIdx.x;
    const int k = b & 7;        // XCD under round-robin dispatch heuristic
    const int m = b >> 3;       // 0..259 local rank within XCD
    int bi, bj;
    if (m < 36) {
        // diagonal group k: 8x8 upper triangle, cum(t) = t*(17-t)/2
        int ti = (int)((17.0f - sqrtf(289.0f - 8.0f * (float)m)) * 0.5f);
        if (m < ti * (17 - ti) / 2) ti--;
        else if (m >= (ti + 1) * (16 - ti) / 2) ti++;
        const int tj = ti + (m - ti * (17 - ti) / 2);
        bi = k * 8 + ti;
        bj = k * 8 + tj;
    } else {
        const int m2 = m - 36;           // 0..223
        const int hh = m2 >> 5;          // 0..6  (which of my 7 halves)
        const int r  = m2 & 31;          // 0..31 within half (4x8 tiles)
        const int h  = hh * 8 + k;       // 0..55 global half index
        const int q  = h >> 1;           // 0..27 off-diag group pair
        const int sub = h & 1;
        // pair q -> (gi,gj), gi<gj<8, cum(gi) = gi*(15-gi)/2
        int gi = 0;
        #pragma unroll
        for (int t = 6; t > 0; --t)
            if (q >= t * (15 - t) / 2) { gi = t; break; }
        const int gj = gi + 1 + (q - gi * (15 - gi) / 2);
        bi = gi * 8 + sub * 4 + (r >> 3);
        bj = gj * 8 + (r & 7);
    }
    const bool diag = (bi == bj);

    // LDS: 8 pieces x 16KB = 128KB, + rs/cs 2KB  (gfx950: 160KB/CU)
    // slot(b,t) = b*4+t, t: 0=A-ks0, 1=A-ks1, 2=B-ks0, 3=B-ks1
    __shared__ alignas(16) __hip_bfloat16 tiles[8 * PIECE];  // 128 KB
    __shared__ float rs[TM];
    __shared__ float cs[TM];

    const int tid  = threadIdx.x;
    const int wave = tid >> 6;            // 0..7
    const int lane = tid & 63;
    const int wm   = wave & 1;            // wave row (0..1): rows wm*128..+128
    const int wn   = wave >> 1;           // wave col (0..3): cols wn*64..+64
    const int g    = lane >> 4;           // quad  (0..3)
    const int m15  = lane & 15;

    if (tid < TM) { rs[tid] = 0.f; cs[tid] = 0.f; }

    // ---- staging addresses (computed once) ----
    // lane l covers LDS row rr = wave*32 + t*16 + (l>>2), lds 16B-slot l&3;
    // swizzled source slot = (l&3) ^ ((l>>3)&3)   [R6-validated, 0 conflicts]
    const int st_r0 = wave * 32 + (lane >> 2);             // t=0 row
    const int st_c  = (lane & 3) ^ ((lane >> 3) & 3);      // source 16B slot
    const __hip_bfloat16* gA = Z + (size_t)(bi * TM + st_r0) * HDIM + st_c * 8;
    const __hip_bfloat16* gB = Z + (size_t)(bj * TM + st_r0) * HDIM + st_c * 8;

    // stage one piece: 2 x global_load_lds (rows wave*32+0..15, +16..31);
    // LDS dest wave-uniform base + lane*16B (linear), source pre-swizzled.
    #define STAGE_P(SLOT, GSRC, KK) do {                                      \
        __hip_bfloat16* _lp = tiles + (SLOT) * PIECE + (wave * 32) * KSUB;    \
        async_copy16((GSRC) + (KK), _lp);                                     \
        async_copy16((GSRC) + (KK) + 16 * HDIM, _lp + 16 * KSUB);             \
    } while (0)

    // ---- fragment read offsets (immediates fold per-phase) ----
    const int sw = g ^ ((m15 >> 1) & 3);
    const int raOff = (wm * 128 + m15) * KSUB + sw * 8;
    const int rbOff = (wn * 64  + m15) * KSUB + sw * 8;

    floatx4 acc[8][4] = {};
    shortx8 bfr[4];   // B frags for current ks, live across the fm-half pair

    #define PHASE(BUF, KS, FMH, STAGES, GATES) do {                           \
        const __hip_bfloat16* _ra = tiles + ((BUF)*4 + (KS)) * PIECE + raOff; \
        shortx8 _af[4];                                                       \
        _Pragma("unroll")                                                     \
        for (int _f = 0; _f < 4; ++_f)                                        \
            _af[_f] = *(const shortx8*)(_ra + ((FMH)*4 + _f) * 16 * KSUB);    \
        if ((FMH) == 0) {                                                     \
            const __hip_bfloat16* _rb =                                       \
                tiles + ((BUF)*4 + 2 + (KS)) * PIECE + rbOff;                 \
            _Pragma("unroll")                                                 \
            for (int _f = 0; _f < 4; ++_f)                                    \
                bfr[_f] = *(const shortx8*)(_rb + _f * 16 * KSUB);            \
        }                                                                     \
        STAGES;                                                               \
        GATES;                                                                \
        RAW_BARRIER();              /* leading */                             \
        __builtin_amdgcn_s_setprio(1);                                        \
        _Pragma("unroll")                                                     \
        for (int _i = 0; _i < 4; ++_i)                                        \
            _Pragma("unroll")                                                 \
            for (int _j = 0; _j < 4; ++_j)                                    \
                acc[(FMH)*4 + _i][_j] = __builtin_amdgcn_mfma_f32_16x16x32_bf16( \
                    _af[_i], bfr[_j], acc[(FMH)*4 + _i][_j], 0, 0, 0);        \
        __builtin_amdgcn_s_setprio(0);                                        \
        RAW_BARRIER();              /* trailing */                            \
    } while (0)

    // ---- prologue: 7 pieces, then gate + barrier ----
    // piece issue #: 1:(0)B0 2:(0)A0 3:(0)B1 4:(0)A1 5:(1)B0 6:(1)A0 7:(1)B1
    STAGE_P(2, gB, 0);      // (0).B-ks0
    STAGE_P(0, gA, 0);      // (0).A-ks0
    STAGE_P(3, gB, 32);     // (0).B-ks1
    STAGE_P(1, gA, 32);     // (0).A-ks1
    STAGE_P(6, gB, 64);     // (1).B-ks0
    STAGE_P(4, gA, 64);     // (1).A-ks0
    STAGE_P(7, gB, 96);     // (1).B-ks1
    GATE(0x0F7A);           // vmcnt(10): #1,#2 retired (kt0 p0/p1 needs)
    RAW_BARRIER();

    // ---- 16 phases; stage #8..#16 per slot-rotation; gates at p1/p3 ----
    // kt0 (buf 0)
    PHASE(0,0,0, STAGE_P(5, gA,  96), NOGATE);        // #8  (1).A1
    PHASE(0,0,1, STAGE_P(2, gB, 128), GATE(0x0F7A));  // #9  (2).B0; cover kt0 p2/p3
    PHASE(0,1,0, STAGE_P(0, gA, 128), NOGATE);        // #10 (2).A0
    PHASE(0,1,1, STAGE_P(3, gB, 160), GATE(0x0F7A));  // #11 (2).B1; cover kt1 p0/p1
    // kt1 (buf 1)
    PHASE(1,0,0, STAGE_P(1, gA, 160), NOGATE);        // #12 (2).A1
    PHASE(1,0,1, STAGE_P(6, gB, 192), GATE(0x0F7A));  // #13 (3).B0; cover kt1 p2/p3
    PHASE(1,1,0, STAGE_P(4, gA, 192), NOGATE);        // #14 (3).A0
    PHASE(1,1,1, STAGE_P(7, gB, 224), GATE(0x0F7A));  // #15 (3).B1; cover kt2 p0/p1
    // kt2 (buf 0)
    PHASE(0,0,0, STAGE_P(5, gA, 224), NOGATE);        // #16 (3).A1
    PHASE(0,0,1, NOSTAGE,             GATE(0x0F78));  // vmcnt(8): cover kt2 p2/p3
    PHASE(0,1,0, NOSTAGE,             NOGATE);
    PHASE(0,1,1, NOSTAGE,             GATE(0x0F74));  // vmcnt(4): cover kt3 p0/p1
    // kt3 (buf 1)
    PHASE(1,0,0, NOSTAGE,             NOGATE);
    PHASE(1,0,1, NOSTAGE,             GATE(0x0F70));  // vmcnt(0): cover kt3 p2/p3
    PHASE(1,1,0, NOSTAGE,             NOGATE);
    PHASE(1,1,1, NOSTAGE,             NOGATE);

    #undef PHASE
    #undef STAGE_P

    // ---- epilogue: e = exp2(acc) (== exp(sim/tau)), reduce rows & cols ----
    float rp[8][4] = {{0.f}};  // [fm][reg] partial row sums
    float cp[4]    = {0.f};    // [fn]      partial col sums

    if (!diag) {
        #pragma unroll
        for (int fm = 0; fm < 8; ++fm)
            #pragma unroll
            for (int fn = 0; fn < 4; ++fn) {
                const floatx4 a = acc[fm][fn];
                #pragma unroll
                for (int q = 0; q < 4; ++q) {
                    const float e = __builtin_amdgcn_exp2f(a[q]);
                    rp[fm][q] += e;
                    cp[fn]    += e;
                }
            }
    } else {
        #pragma unroll
        for (int fm = 0; fm < 8; ++fm)
            #pragma unroll
            for (int fn = 0; fn < 4; ++fn) {
                const floatx4 a = acc[fm][fn];
                const int cl = wn * 64 + fn * 16 + m15;
                #pragma unroll
                for (int q = 0; q < 4; ++q) {
                    const int rl = wm * 128 + fm * 16 + g * 4 + q;
                    float e = __builtin_amdgcn_exp2f(a[q]);
                    if (cl <= rl) e = 0.f;   // strictly-upper only
                    rp[fm][q] += e;
                    cp[fn]    += e;
                }
            }
    }

    // row sums: 16-lane DPP reduction (VALU pipe); total lands in m15==0
    #pragma unroll
    for (int fm = 0; fm < 8; ++fm)
        #pragma unroll
        for (int q = 0; q < 4; ++q) {
            float v = rp[fm][q];
            DPP_ROW_SHL_ADD(v, 0x101);   // row_shl:1
            DPP_ROW_SHL_ADD(v, 0x102);   // row_shl:2
            DPP_ROW_SHL_ADD(v, 0x104);   // row_shl:4
            DPP_ROW_SHL_ADD(v, 0x108);   // row_shl:8
            rp[fm][q] = v;
        }
    if (m15 == 0) {
        #pragma unroll
        for (int fm = 0; fm < 8; ++fm)
            #pragma unroll
            for (int q = 0; q < 4; ++q)
                atomicAdd(&rs[wm * 128 + fm * 16 + g * 4 + q], rp[fm][q]);
    }

    // col sums: reduce across quads (xor 16/32 crosses DPP rows -> keep shfl)
    #pragma unroll
    for (int mask = 16; mask < 64; mask <<= 1)
        #pragma unroll
        for (int fn = 0; fn < 4; ++fn)
            cp[fn] += __shfl_xor(cp[fn], mask);
    if (g == 0) {
        #pragma unroll
        for (int fn = 0; fn < 4; ++fn)
            atomicAdd(&cs[wn * 64 + fn * 16 + m15], cp[fn]);
    }

    __syncthreads();
    if (tid < TM) {
        atomicAdd(&rowsum[(size_t)bi * TM + tid], rs[tid]);
        atomicAdd(&rowsum[(size_t)bj * TM + tid], cs[tid]);
    }
}

// ---------------------------------------------------------------------------
// Kernel 3: loss = mean( log(rowsum_i) - 2*pos_i ), 16 blocks + atomic.
// out[0] zeroed by normalize_kernel (stream-ordered).
// ---------------------------------------------------------------------------
__global__ __launch_bounds__(1024) void finalize_kernel(
    const float* __restrict__ rowsum, const float* __restrict__ pos,
    float* __restrict__ out)
{
    const int i = threadIdx.x + blockIdx.x * 1024;
    float s = logf(rowsum[i]) - 2.0f * pos[i];
    #pragma unroll
    for (int off = 32; off; off >>= 1) s += __shfl_down(s, off);
    __shared__ float sh[16];
    const int lt = threadIdx.x;
    if ((lt & 63) == 0) sh[lt >> 6] = s;
    __syncthreads();
    if (lt == 0) {
        float tot = 0.f;
        #pragma unroll
        for (int w = 0; w < 16; ++w) tot += sh[w];
        atomicAdd(out, tot / (float)N2);
    }
}

// ---------------------------------------------------------------------------
extern "C" void kernel_launch(void* const* d_in, const int* in_sizes, int n_in,
                              void* d_out, int out_size, void* d_ws, size_t ws_size,
                              hipStream_t stream)
{
    const float* x = (const float*)d_in[0];
    const float* y = (const float*)d_in[1];

    // workspace: Z bf16 [16384*256] (8 MB) | rowsum f32 [16384] | pos f32 [16384]
    __hip_bfloat16* Z = (__hip_bfloat16*)d_ws;
    float* rowsum = (float*)((char*)d_ws + (size_t)N2 * HDIM * sizeof(__hip_bfloat16));
    float* pos    = rowsum + N2;

    normalize_kernel<<<NROWS / 4, 256, 0, stream>>>(x, y, Z, pos, rowsum, (float*)d_out);
    simgemm_kernel<<<NBLK, 512, 0, stream>>>(Z, rowsum);
    finalize_kernel<<<N2 / 1024, 1024, 0, stream>>>(rowsum, pos, (float*)d_out);
}

// Round 5
// 159.456 us; speedup vs baseline: 1.0425x; 1.0425x over previous
//
#include <hip/hip_runtime.h>
#include <hip/hip_bf16.h>
#include <math.h>

// Problem constants (fixed by reference setup_inputs)
constexpr int NROWS = 8192;   // B
constexpr int HDIM  = 256;    // H (= K of the GEMM)
constexpr int N2    = 16384;  // 2*B rows of Z
constexpr int TM    = 256;    // tile M = tile N (256x256, 8 waves of 128x64)
constexpr int BK    = 32;     // K chunk staged per round (8 chunks)
constexpr int NCHUNK = HDIM / BK;     // 8
constexpr int PIECE = TM * BK;        // 8192 elems = 16 KB per piece
constexpr int NTILE = N2 / TM;        // 64 tile-rows
constexpr int NBLK  = NTILE * (NTILE + 1) / 2;  // 2080 upper-tri tiles

// sqrt(2 * log2(e)): Z pre-scaled so Zs_i.Zs_j = 2*log2(e)*cos and
// exp2(acc) == exp(sim/tau), tau = 0.5
constexpr float PRESCALE = 1.69864357f;

typedef __attribute__((ext_vector_type(4))) float floatx4;
typedef __attribute__((ext_vector_type(8))) short shortx8; // 8 bf16 = 4 VGPRs

__device__ __forceinline__ void async_copy16(const void* gptr, void* lptr) {
    __builtin_amdgcn_global_load_lds(
        (const __attribute__((address_space(1))) unsigned int*)gptr,
        (__attribute__((address_space(3))) unsigned int*)lptr, 16, 0, 0);
}

// s_waitcnt immediates (gfx9: vm[3:0], exp[6:4], lgkm[11:8], vm-hi[15:14])
#define WAIT_VM0()   __builtin_amdgcn_s_waitcnt(0x0F70)  // vmcnt(0)
#define MEMFENCE()   __asm__ __volatile__("" ::: "memory")
#define RAW_BARRIER() do { MEMFENCE(); __builtin_amdgcn_s_barrier(); MEMFENCE(); } while (0)

// DPP row_shl add: VALU pipe, not DS (R9: -18us vs ds_bpermute shuffles).
#define DPP_ROW_SHL_ADD(v, CTRL) do {                                        \
    union { float f; int i; } _u, _r; _u.f = (v);                            \
    _r.i = __builtin_amdgcn_update_dpp(0, _u.i, (CTRL), 0xF, 0xF, true);     \
    (v) += _r.f; } while (0)

// ---------------------------------------------------------------------------
// Kernel 1: wave-per-row L2-normalize -> bf16 Z (pre-scaled); pos = cos(x,y).
// Also zeroes rowsum and out (stream-ordered before consumers).
// ---------------------------------------------------------------------------
__global__ __launch_bounds__(256) void normalize_kernel(
    const float* __restrict__ x, const float* __restrict__ y,
    __hip_bfloat16* __restrict__ Z, float* __restrict__ pos,
    float* __restrict__ rowsum, float* __restrict__ out)
{
    const int wave = threadIdx.x >> 6, lane = threadIdx.x & 63;
    const int row  = blockIdx.x * 4 + wave;           // grid 2048 -> 8192 rows

    const float4 xv = ((const float4*)x)[row * 64 + lane];
    const float4 yv = ((const float4*)y)[row * 64 + lane];

    float sx  = xv.x*xv.x + xv.y*xv.y + xv.z*xv.z + xv.w*xv.w;
    float sy  = yv.x*yv.x + yv.y*yv.y + yv.z*yv.z + yv.w*yv.w;
    float sxy = xv.x*yv.x + xv.y*yv.y + xv.z*yv.z + xv.w*yv.w;
    #pragma unroll
    for (int m = 1; m < 64; m <<= 1) {
        sx  += __shfl_xor(sx,  m);
        sy  += __shfl_xor(sy,  m);
        sxy += __shfl_xor(sxy, m);
    }
    const float rxn = rsqrtf(sx), ryn = rsqrtf(sy);
    const float rx = rxn * PRESCALE, ry = ryn * PRESCALE;

    union { ushort4 u; __hip_bfloat16 h[4]; } zx, zy;
    zx.h[0] = __float2bfloat16(xv.x * rx); zx.h[1] = __float2bfloat16(xv.y * rx);
    zx.h[2] = __float2bfloat16(xv.z * rx); zx.h[3] = __float2bfloat16(xv.w * rx);
    zy.h[0] = __float2bfloat16(yv.x * ry); zy.h[1] = __float2bfloat16(yv.y * ry);
    zy.h[2] = __float2bfloat16(yv.z * ry); zy.h[3] = __float2bfloat16(yv.w * ry);
    ((ushort4*)Z)[row * 64 + lane]             = zx.u;
    ((ushort4*)Z)[(row + NROWS) * 64 + lane]   = zy.u;

    if (lane == 0) {
        const float p = sxy * rxn * ryn;
        pos[row]         = p;
        pos[row + NROWS] = p;
    }
    const int gt = blockIdx.x * 256 + threadIdx.x;
    if (gt < N2) rowsum[gt] = 0.f;
    if (gt == 0) out[0] = 0.f;
}

// ---------------------------------------------------------------------------
// Kernel 2: upper-triangle tiled Z·Z^T, fused exp2 + row/col sums.
// R14: 256^2 tile, TWO LDS buffers (66KB) -> 2 blocks/CU co-resident.
// Diagnosis after R10-R13 (all schedule variants pin at 24-29% MfmaUtil;
// depth-1 == depth-2; LDS-BW ceiling ~90% — none binding): the pin is
// thin lockstep wave supply (2 waves/SIMD in the same phase) plus serial
// per-block edges (prologue stage-wait, ~3-4k-cyc VALU epilogue = the
// VALUBusy 30%) with NO inter-block overlap at 1 block/CU. 2 blocks/CU
// gives 4 waves/SIMD from INDEPENDENT blocks: B's MFMA fills A's
// barrier/latency/epilogue gaps (m114 co-scheduling); dispatch tail halves.
// Register feasibility: acc 128 AGPR + ~112 VGPR = 240 combined/wave;
// 4 waves/SIMD x 240 = 960 <= 2048 pool. LDS binder removed: 64KB tiles
// + 2KB rs/cs = 66KB; 2x66 <= 160KB.
// Schedule (2-buffer WAR-safe variant):
//   body s: WAIT_VM0 (chunk-s loads, issued body s-1, ~1 chunk lead);
//           BARRIER; STAGE(s+1) -> buf (s+1)&1   [= buf read in body s-1;
//           all waves' body-(s-1) ds_reads retired before this barrier:
//           compiler lgkm gates precede their MFMAs, DS retires in-order];
//           ds_read buf s&1; setprio(1); 32 MFMA; setprio(0).
// Stage must sit AFTER the barrier with 2 buffers (before it, another
// wave may still have body-(s-1) reads in flight on the dest buffer).
// No device-scope fences (R5). No direct-from-global frags (R7).
// ---------------------------------------------------------------------------
__global__ __launch_bounds__(512, 2) void simgemm_kernel(
    const __hip_bfloat16* __restrict__ Z, float* __restrict__ rowsum)
{
    // ---- XCD-local block -> (bi,bj) mapping (bijection onto upper tri) ----
    // 2080 = 8 XCDs x 260; per XCD: 36 diag-group tiles + 7 off-diag halves(4x8)
    const int b = blockIdx.x;
    const int k = b & 7;        // XCD under round-robin dispatch heuristic
    const int m = b >> 3;       // 0..259 local rank within XCD
    int bi, bj;
    if (m < 36) {
        // diagonal group k: 8x8 upper triangle, cum(t) = t*(17-t)/2
        int ti = (int)((17.0f - sqrtf(289.0f - 8.0f * (float)m)) * 0.5f);
        if (m < ti * (17 - ti) / 2) ti--;
        else if (m >= (ti + 1) * (16 - ti) / 2) ti++;
        const int tj = ti + (m - ti * (17 - ti) / 2);
        bi = k * 8 + ti;
        bj = k * 8 + tj;
    } else {
        const int m2 = m - 36;           // 0..223
        const int hh = m2 >> 5;          // 0..6  (which of my 7 halves)
        const int r  = m2 & 31;          // 0..31 within half (4x8 tiles)
        const int h  = hh * 8 + k;       // 0..55 global half index
        const int q  = h >> 1;           // 0..27 off-diag group pair
        const int sub = h & 1;
        // pair q -> (gi,gj), gi<gj<8, cum(gi) = gi*(15-gi)/2
        int gi = 0;
        #pragma unroll
        for (int t = 6; t > 0; --t)
            if (q >= t * (15 - t) / 2) { gi = t; break; }
        const int gj = gi + 1 + (q - gi * (15 - gi) / 2);
        bi = gi * 8 + sub * 4 + (r >> 3);
        bj = gj * 8 + (r & 7);
    }
    const bool diag = (bi == bj);

    // LDS: 2 buffers x (tA 16KB + tB 16KB) = 64KB, + rs/cs 2KB = 66KB
    __shared__ alignas(16) __hip_bfloat16 tiles[4 * PIECE];  // 64 KB
    __shared__ float rs[TM];
    __shared__ float cs[TM];
    __hip_bfloat16* tA = tiles;                  // + buf * 2*PIECE
    __hip_bfloat16* tB = tiles + PIECE;          // + buf * 2*PIECE

    const int tid  = threadIdx.x;
    const int wave = tid >> 6;            // 0..7
    const int lane = tid & 63;
    const int wm   = wave & 1;            // wave row (0..1): rows wm*128..+128
    const int wn   = wave >> 1;           // wave col (0..3): cols wn*64..+64
    const int g    = lane >> 4;           // quad  (0..3)
    const int m15  = lane & 15;

    if (tid < TM) { rs[tid] = 0.f; cs[tid] = 0.f; }

    // ---- staging addresses (computed once) ----
    // lane l covers LDS row rr = wave*32 + t*16 + (l>>2), lds chunk l&3;
    // swizzled source chunk = (l&3) ^ ((l>>3)&3)   [R6-validated, 0 conflicts]
    const int st_r0  = wave * 32 + (lane >> 2);            // t=0 row
    const int st_c   = (lane & 3) ^ ((lane >> 3) & 3);     // source chunk
    const __hip_bfloat16* gA0 = Z + (size_t)(bi * TM + st_r0) * HDIM + st_c * 8;
    const __hip_bfloat16* gA1 = gA0 + 16 * HDIM;           // t=1 rows
    const __hip_bfloat16* gB0 = Z + (size_t)(bj * TM + st_r0) * HDIM + st_c * 8;
    const __hip_bfloat16* gB1 = gB0 + 16 * HDIM;
    // wave-uniform LDS bases (lane scatter is +l*16B)
    __hip_bfloat16* lA0 = tA + (wave * 32) * BK;
    __hip_bfloat16* lA1 = tA + (wave * 32 + 16) * BK;
    __hip_bfloat16* lB0 = tB + (wave * 32) * BK;
    __hip_bfloat16* lB1 = tB + (wave * 32 + 16) * BK;

    // ---- fragment read addresses (all f-offsets immediates) ----
    const int sw = g ^ ((m15 >> 1) & 3);
    const __hip_bfloat16* rA = tA + (wm * 128 + m15) * BK + sw * 8;
    const __hip_bfloat16* rB = tB + (wn * 64  + m15) * BK + sw * 8;

    floatx4 acc[8][4] = {};

    // chunk ck -> buffer ck&1; global offset ck*BK folds to imm
    #define STAGE(ck)  do {                                                  \
        const int _o = ((ck) & 1) * 2 * PIECE;                               \
        async_copy16(gA0 + (ck) * BK, lA0 + _o);                             \
        async_copy16(gA1 + (ck) * BK, lA1 + _o);                             \
        async_copy16(gB0 + (ck) * BK, lB0 + _o);                             \
        async_copy16(gB1 + (ck) * BK, lB1 + _o);                             \
    } while (0)

    STAGE(0);   // prologue (only chunk 0 in flight entering body 0)

    #pragma unroll
    for (int s = 0; s < NCHUNK; ++s) {
        WAIT_VM0();      // chunk-s loads (sole outstanding) retired, per-wave
        RAW_BARRIER();   // collectivize: buf s&1 fully landed for all waves
        if (s + 1 < NCHUNK) STAGE(s + 1);   // AFTER barrier: WAR-safe (hdr)

        const int bo = (s & 1) * 2 * PIECE;
        shortx8 af[8], bfr[4];
        #pragma unroll
        for (int f = 0; f < 8; ++f)
            af[f]  = *(const shortx8*)(rA + bo + f * 16 * BK);
        #pragma unroll
        for (int f = 0; f < 4; ++f)
            bfr[f] = *(const shortx8*)(rB + bo + f * 16 * BK);

        __builtin_amdgcn_s_setprio(1);
        #pragma unroll
        for (int fm = 0; fm < 8; ++fm)
            #pragma unroll
            for (int fn = 0; fn < 4; ++fn)
                acc[fm][fn] = __builtin_amdgcn_mfma_f32_16x16x32_bf16(
                    af[fm], bfr[fn], acc[fm][fn], 0, 0, 0);
        __builtin_amdgcn_s_setprio(0);
    }
    #undef STAGE

    // ---- epilogue: e = exp2(acc) (== exp(sim/tau)), reduce rows & cols ----
    float rp[8][4] = {{0.f}};  // [fm][reg] partial row sums
    float cp[4]    = {0.f};    // [fn]      partial col sums

    if (!diag) {
        #pragma unroll
        for (int fm = 0; fm < 8; ++fm)
            #pragma unroll
            for (int fn = 0; fn < 4; ++fn) {
                const floatx4 a = acc[fm][fn];
                #pragma unroll
                for (int q = 0; q < 4; ++q) {
                    const float e = __builtin_amdgcn_exp2f(a[q]);
                    rp[fm][q] += e;
                    cp[fn]    += e;
                }
            }
    } else {
        #pragma unroll
        for (int fm = 0; fm < 8; ++fm)
            #pragma unroll
            for (int fn = 0; fn < 4; ++fn) {
                const floatx4 a = acc[fm][fn];
                const int cl = wn * 64 + fn * 16 + m15;
                #pragma unroll
                for (int q = 0; q < 4; ++q) {
                    const int rl = wm * 128 + fm * 16 + g * 4 + q;
                    float e = __builtin_amdgcn_exp2f(a[q]);
                    if (cl <= rl) e = 0.f;   // strictly-upper only
                    rp[fm][q] += e;
                    cp[fn]    += e;
                }
            }
    }

    // row sums: 16-lane DPP reduction (VALU pipe); total lands in m15==0
    #pragma unroll
    for (int fm = 0; fm < 8; ++fm)
        #pragma unroll
        for (int q = 0; q < 4; ++q) {
            float v = rp[fm][q];
            DPP_ROW_SHL_ADD(v, 0x101);   // row_shl:1
            DPP_ROW_SHL_ADD(v, 0x102);   // row_shl:2
            DPP_ROW_SHL_ADD(v, 0x104);   // row_shl:4
            DPP_ROW_SHL_ADD(v, 0x108);   // row_shl:8
            rp[fm][q] = v;
        }
    if (m15 == 0) {
        #pragma unroll
        for (int fm = 0; fm < 8; ++fm)
            #pragma unroll
            for (int q = 0; q < 4; ++q)
                atomicAdd(&rs[wm * 128 + fm * 16 + g * 4 + q], rp[fm][q]);
    }

    // col sums: reduce across quads (xor 16/32 crosses DPP rows -> keep shfl)
    #pragma unroll
    for (int mask = 16; mask < 64; mask <<= 1)
        #pragma unroll
        for (int fn = 0; fn < 4; ++fn)
            cp[fn] += __shfl_xor(cp[fn], mask);
    if (g == 0) {
        #pragma unroll
        for (int fn = 0; fn < 4; ++fn)
            atomicAdd(&cs[wn * 64 + fn * 16 + m15], cp[fn]);
    }

    __syncthreads();
    if (tid < TM) {
        atomicAdd(&rowsum[(size_t)bi * TM + tid], rs[tid]);
        atomicAdd(&rowsum[(size_t)bj * TM + tid], cs[tid]);
    }
}

// ---------------------------------------------------------------------------
// Kernel 3: loss = mean( log(rowsum_i) - 2*pos_i ), 16 blocks + atomic.
// out[0] zeroed by normalize_kernel (stream-ordered).
// ---------------------------------------------------------------------------
__global__ __launch_bounds__(1024) void finalize_kernel(
    const float* __restrict__ rowsum, const float* __restrict__ pos,
    float* __restrict__ out)
{
    const int i = threadIdx.x + blockIdx.x * 1024;
    float s = logf(rowsum[i]) - 2.0f * pos[i];
    #pragma unroll
    for (int off = 32; off; off >>= 1) s += __shfl_down(s, off);
    __shared__ float sh[16];
    const int lt = threadIdx.x;
    if ((lt & 63) == 0) sh[lt >> 6] = s;
    __syncthreads();
    if (lt == 0) {
        float tot = 0.f;
        #pragma unroll
        for (int w = 0; w < 16; ++w) tot += sh[w];
        atomicAdd(out, tot / (float)N2);
    }
}

// ---------------------------------------------------------------------------
extern "C" void kernel_launch(void* const* d_in, const int* in_sizes, int n_in,
                              void* d_out, int out_size, void* d_ws, size_t ws_size,
                              hipStream_t stream)
{
    const float* x = (const float*)d_in[0];
    const float* y = (const float*)d_in[1];

    // workspace: Z bf16 [16384*256] (8 MB) | rowsum f32 [16384] | pos f32 [16384]
    __hip_bfloat16* Z = (__hip_bfloat16*)d_ws;
    float* rowsum = (float*)((char*)d_ws + (size_t)N2 * HDIM * sizeof(__hip_bfloat16));
    float* pos    = rowsum + N2;

    normalize_kernel<<<NROWS / 4, 256, 0, stream>>>(x, y, Z, pos, rowsum, (float*)d_out);
    simgemm_kernel<<<NBLK, 512, 0, stream>>>(Z, rowsum);
    finalize_kernel<<<N2 / 1024, 1024, 0, stream>>>(rowsum, pos, (float*)d_out);
}

// Round 7
// 153.874 us; speedup vs baseline: 1.0803x; 1.0363x over previous
//
#include <hip/hip_runtime.h>
#include <hip/hip_bf16.h>
#include <math.h>

// Problem constants (fixed by reference setup_inputs)
constexpr int NROWS = 8192;   // B
constexpr int HDIM  = 256;    // H (= K of the GEMM)
constexpr int N2    = 16384;  // 2*B rows of Z
constexpr int TM    = 256;    // tile M = tile N (256x256, 8 waves of 128x64)
constexpr int BK    = 32;     // K chunk staged per round (8 chunks)
constexpr int NCHUNK = HDIM / BK;     // 8
constexpr int PIECE = TM * BK;        // 8192 elems = 16 KB per piece
constexpr int NTILE = N2 / TM;        // 64 tile-rows
constexpr int NBLK  = NTILE * (NTILE + 1) / 2;  // 2080 upper-tri tiles

// sqrt(2 * log2(e)): Z pre-scaled so Zs_i.Zs_j = 2*log2(e)*cos and
// exp2(acc) == exp(sim/tau), tau = 0.5
constexpr float PRESCALE = 1.69864357f;

typedef __attribute__((ext_vector_type(4))) float floatx4;
typedef __attribute__((ext_vector_type(8))) short shortx8; // 8 bf16 = 4 VGPRs

__device__ __forceinline__ void async_copy16(const void* gptr, void* lptr) {
    __builtin_amdgcn_global_load_lds(
        (const __attribute__((address_space(1))) unsigned int*)gptr,
        (__attribute__((address_space(3))) unsigned int*)lptr, 16, 0, 0);
}

// s_waitcnt immediates (gfx9: vm[3:0], exp[6:4], lgkm[11:8], vm-hi[15:14])
#define GATE(IMM)    __builtin_amdgcn_s_waitcnt(IMM)
#define WAIT_VM0()   __builtin_amdgcn_s_waitcnt(0x0F70)  // vmcnt(0)
#define MEMFENCE()   __asm__ __volatile__("" ::: "memory")
#define RAW_BARRIER() do { MEMFENCE(); __builtin_amdgcn_s_barrier(); MEMFENCE(); } while (0)

// DPP row_shl add: VALU pipe, not DS (R9: -18us vs ds_bpermute shuffles).
#define DPP_ROW_SHL_ADD(v, CTRL) do {                                        \
    union { float f; int i; } _u, _r; _u.f = (v);                            \
    _r.i = __builtin_amdgcn_update_dpp(0, _u.i, (CTRL), 0xF, 0xF, true);     \
    (v) += _r.f; } while (0)

// ---------------------------------------------------------------------------
// Kernel 1: wave-per-row L2-normalize -> bf16 Z (pre-scaled); pos = cos(x,y).
// Also zeroes rowsum and out (stream-ordered before consumers).
// ---------------------------------------------------------------------------
__global__ __launch_bounds__(256) void normalize_kernel(
    const float* __restrict__ x, const float* __restrict__ y,
    __hip_bfloat16* __restrict__ Z, float* __restrict__ pos,
    float* __restrict__ rowsum, float* __restrict__ out)
{
    const int wave = threadIdx.x >> 6, lane = threadIdx.x & 63;
    const int row  = blockIdx.x * 4 + wave;           // grid 2048 -> 8192 rows

    const float4 xv = ((const float4*)x)[row * 64 + lane];
    const float4 yv = ((const float4*)y)[row * 64 + lane];

    float sx  = xv.x*xv.x + xv.y*xv.y + xv.z*xv.z + xv.w*xv.w;
    float sy  = yv.x*yv.x + yv.y*yv.y + yv.z*yv.z + yv.w*yv.w;
    float sxy = xv.x*yv.x + xv.y*yv.y + xv.z*yv.z + xv.w*yv.w;
    #pragma unroll
    for (int m = 1; m < 64; m <<= 1) {
        sx  += __shfl_xor(sx,  m);
        sy  += __shfl_xor(sy,  m);
        sxy += __shfl_xor(sxy, m);
    }
    const float rxn = rsqrtf(sx), ryn = rsqrtf(sy);
    const float rx = rxn * PRESCALE, ry = ryn * PRESCALE;

    union { ushort4 u; __hip_bfloat16 h[4]; } zx, zy;
    zx.h[0] = __float2bfloat16(xv.x * rx); zx.h[1] = __float2bfloat16(xv.y * rx);
    zx.h[2] = __float2bfloat16(xv.z * rx); zx.h[3] = __float2bfloat16(xv.w * rx);
    zy.h[0] = __float2bfloat16(yv.x * ry); zy.h[1] = __float2bfloat16(yv.y * ry);
    zy.h[2] = __float2bfloat16(yv.z * ry); zy.h[3] = __float2bfloat16(yv.w * ry);
    ((ushort4*)Z)[row * 64 + lane]             = zx.u;
    ((ushort4*)Z)[(row + NROWS) * 64 + lane]   = zy.u;

    if (lane == 0) {
        const float p = sxy * rxn * ryn;
        pos[row]         = p;
        pos[row + NROWS] = p;
    }
    const int gt = blockIdx.x * 256 + threadIdx.x;
    if (gt < N2) rowsum[gt] = 0.f;
    if (gt == 0) out[0] = 0.f;
}

// ---------------------------------------------------------------------------
// Kernel 2: upper-triangle tiled Z·Z^T, fused exp2 + row/col sums.
// R15 (resubmitted after infra failure — kernel audited: no waitcnt
// deadlock, no barrier divergence, no OOB, LDS 98KB, regs ~250<=256):
// software-pipelined fragment reads (modulo schedule, depth 1).
// Diagnosis closing R10-R14's invariant 27% MfmaUtil: per chunk per CU,
// LDS traffic = 96KB frag reads + 32KB stage writes ~ 1300 cyc at ~100B/cyc
// vs 1024 cyc MFMA — co-critical — and ALL prior schedules serialized the
// read window and the MFMA burst on opposite sides of the same barrier
// (first MFMA depends on the last B-frag read). Fix: body s holds chunk-s
// frags in REGISTERS; reads for chunk s+1 are issued BEFORE chunk-s's MFMA
// burst, so LDS data-return overlaps MFMA (compiler lgkm-gates them before
// body s+1's MFMAs).
//   body s: vm0 [chunk s+1 loads, sole outstanding, ~1 body lead]; BARRIER
//           [buf (s+1)%3 ready for all]; read bfN (4x b128, chunk s+1);
//           STAGE(s+2) -> buf (s+2)%3; MFMA fm0..3 (chunk s);
//           read af[0..3] <- chunk s+1 (overwrite, WAR-by-issue-order);
//           MFMA fm4..7 (chunk s); read af[4..7] <- chunk s+1.
// Register discipline (unified file, 256/wave cap for 2 waves/SIMD):
// only bfr ping-pongs (+16 VGPR); af overwritten in place after the MFMA
// half consuming it. Peak ~ 128 acc + 64 frag + ~55 misc = 247.
// WAR for STAGE(s+2)->buf (s-1)%3: all waves past BARRIER(s) issued their
// body-(s-1) MFMAs, whose lgkm gates imply chunk-(s-1) reads retired;
// stage is issued after that barrier. RAW: vm0+barrier covers chunk s+1.
// LDS 98KB -> 1 block/CU (inter-block TLP shown ineffective in R9/R14).
// ---------------------------------------------------------------------------
__global__ __launch_bounds__(512, 2) void simgemm_kernel(
    const __hip_bfloat16* __restrict__ Z, float* __restrict__ rowsum)
{
    // ---- XCD-local block -> (bi,bj) mapping (bijection onto upper tri) ----
    // 2080 = 8 XCDs x 260; per XCD: 36 diag-group tiles + 7 off-diag halves(4x8)
    const int b = blockIdx.x;
    const int k = b & 7;        // XCD under round-robin dispatch heuristic
    const int m = b >> 3;       // 0..259 local rank within XCD
    int bi, bj;
    if (m < 36) {
        // diagonal group k: 8x8 upper triangle, cum(t) = t*(17-t)/2
        int ti = (int)((17.0f - sqrtf(289.0f - 8.0f * (float)m)) * 0.5f);
        if (m < ti * (17 - ti) / 2) ti--;
        else if (m >= (ti + 1) * (16 - ti) / 2) ti++;
        const int tj = ti + (m - ti * (17 - ti) / 2);
        bi = k * 8 + ti;
        bj = k * 8 + tj;
    } else {
        const int m2 = m - 36;           // 0..223
        const int hh = m2 >> 5;          // 0..6  (which of my 7 halves)
        const int r  = m2 & 31;          // 0..31 within half (4x8 tiles)
        const int h  = hh * 8 + k;       // 0..55 global half index
        const int q  = h >> 1;           // 0..27 off-diag group pair
        const int sub = h & 1;
        // pair q -> (gi,gj), gi<gj<8, cum(gi) = gi*(15-gi)/2
        int gi = 0;
        #pragma unroll
        for (int t = 6; t > 0; --t)
            if (q >= t * (15 - t) / 2) { gi = t; break; }
        const int gj = gi + 1 + (q - gi * (15 - gi) / 2);
        bi = gi * 8 + sub * 4 + (r >> 3);
        bj = gj * 8 + (r & 7);
    }
    const bool diag = (bi == bj);

    // LDS: 3 buffers x (tA 16KB + tB 16KB) = 96KB, + rs/cs 2KB = 98KB
    __shared__ alignas(16) __hip_bfloat16 tiles[6 * PIECE];  // 96 KB
    __shared__ float rs[TM];
    __shared__ float cs[TM];
    __hip_bfloat16* tA = tiles;                  // + buf * 2*PIECE
    __hip_bfloat16* tB = tiles + PIECE;          // + buf * 2*PIECE

    const int tid  = threadIdx.x;
    const int wave = tid >> 6;            // 0..7
    const int lane = tid & 63;
    const int wm   = wave & 1;            // wave row (0..1): rows wm*128..+128
    const int wn   = wave >> 1;           // wave col (0..3): cols wn*64..+64
    const int g    = lane >> 4;           // quad  (0..3)
    const int m15  = lane & 15;

    if (tid < TM) { rs[tid] = 0.f; cs[tid] = 0.f; }

    // ---- staging addresses (computed once) ----
    // lane l covers LDS row rr = wave*32 + t*16 + (l>>2), lds chunk l&3;
    // swizzled source chunk = (l&3) ^ ((l>>3)&3)   [R6-validated, 0 conflicts]
    const int st_r0  = wave * 32 + (lane >> 2);            // t=0 row
    const int st_c   = (lane & 3) ^ ((lane >> 3) & 3);     // source chunk
    const __hip_bfloat16* gA0 = Z + (size_t)(bi * TM + st_r0) * HDIM + st_c * 8;
    const __hip_bfloat16* gA1 = gA0 + 16 * HDIM;           // t=1 rows
    const __hip_bfloat16* gB0 = Z + (size_t)(bj * TM + st_r0) * HDIM + st_c * 8;
    const __hip_bfloat16* gB1 = gB0 + 16 * HDIM;
    // wave-uniform LDS bases (lane scatter is +l*16B)
    __hip_bfloat16* lA0 = tA + (wave * 32) * BK;
    __hip_bfloat16* lA1 = tA + (wave * 32 + 16) * BK;
    __hip_bfloat16* lB0 = tB + (wave * 32) * BK;
    __hip_bfloat16* lB1 = tB + (wave * 32 + 16) * BK;

    // ---- fragment read addresses (all f-offsets immediates) ----
    const int sw = g ^ ((m15 >> 1) & 3);
    const __hip_bfloat16* rA = tA + (wm * 128 + m15) * BK + sw * 8;
    const __hip_bfloat16* rB = tB + (wn * 64  + m15) * BK + sw * 8;

    floatx4 acc[8][4] = {};
    shortx8 af[8], bfA[4], bfB[4];

    // chunk ck -> buffer ck%3; global offset ck*BK folds to imm
    #define STAGE(ck)  do {                                                  \
        const int _o = ((ck) % 3) * 2 * PIECE;                               \
        async_copy16(gA0 + (ck) * BK, lA0 + _o);                             \
        async_copy16(gA1 + (ck) * BK, lA1 + _o);                             \
        async_copy16(gB0 + (ck) * BK, lB0 + _o);                             \
        async_copy16(gB1 + (ck) * BK, lB1 + _o);                             \
    } while (0)

    // ---- prologue: chunks 0,1 in flight; read chunk-0 frags ----
    STAGE(0);
    STAGE(1);
    GATE(0x0F74);          // vmcnt(4): chunk 0 landed (chunk 1 stays in flight)
    RAW_BARRIER();
    #pragma unroll
    for (int f = 0; f < 4; ++f)
        bfA[f] = *(const shortx8*)(rB + f * 16 * BK);
    #pragma unroll
    for (int f = 0; f < 8; ++f)
        af[f] = *(const shortx8*)(rA + f * 16 * BK);

    // ---- pipelined bodies: MFMA(chunk S) overlaps reads(chunk S+1) ----
    #define BODY(S, BFC, BFN) do {                                           \
        WAIT_VM0();      /* chunk S+1 loads (sole outstanding) retired */    \
        RAW_BARRIER();   /* buf (S+1)%3 ready for ALL waves */               \
        const int _bo = (((S) + 1) % 3) * 2 * PIECE;                         \
        _Pragma("unroll")                                                    \
        for (int f = 0; f < 4; ++f)                                          \
            BFN[f] = *(const shortx8*)(rB + _bo + f * 16 * BK);              \
        if ((S) + 2 < NCHUNK) STAGE((S) + 2);                                \
        __builtin_amdgcn_s_setprio(1);                                       \
        _Pragma("unroll")                                                    \
        for (int fm = 0; fm < 4; ++fm)                                       \
            _Pragma("unroll")                                                \
            for (int fn = 0; fn < 4; ++fn)                                   \
                acc[fm][fn] = __builtin_amdgcn_mfma_f32_16x16x32_bf16(       \
                    af[fm], BFC[fn], acc[fm][fn], 0, 0, 0);                  \
        __builtin_amdgcn_s_setprio(0);                                       \
        _Pragma("unroll")                                                    \
        for (int f = 0; f < 4; ++f)      /* af[0..3] dead -> chunk S+1 */    \
            af[f] = *(const shortx8*)(rA + _bo + f * 16 * BK);               \
        __builtin_amdgcn_s_setprio(1);                                       \
        _Pragma("unroll")                                                    \
        for (int fm = 4; fm < 8; ++fm)                                       \
            _Pragma("unroll")                                                \
            for (int fn = 0; fn < 4; ++fn)                                   \
                acc[fm][fn] = __builtin_amdgcn_mfma_f32_16x16x32_bf16(       \
                    af[fm], BFC[fn], acc[fm][fn], 0, 0, 0);                  \
        __builtin_amdgcn_s_setprio(0);                                       \
        _Pragma("unroll")                                                    \
        for (int f = 4; f < 8; ++f)      /* af[4..7] dead -> chunk S+1 */    \
            af[f] = *(const shortx8*)(rA + _bo + f * 16 * BK);               \
    } while (0)

    BODY(0, bfA, bfB);
    BODY(1, bfB, bfA);
    BODY(2, bfA, bfB);
    BODY(3, bfB, bfA);
    BODY(4, bfA, bfB);
    BODY(5, bfB, bfA);
    BODY(6, bfA, bfB);
    // tail: chunk 7 frags are in af / bfB (read during BODY(6))
    __builtin_amdgcn_s_setprio(1);
    #pragma unroll
    for (int fm = 0; fm < 8; ++fm)
        #pragma unroll
        for (int fn = 0; fn < 4; ++fn)
            acc[fm][fn] = __builtin_amdgcn_mfma_f32_16x16x32_bf16(
                af[fm], bfB[fn], acc[fm][fn], 0, 0, 0);
    __builtin_amdgcn_s_setprio(0);
    #undef BODY
    #undef STAGE

    // ---- epilogue: e = exp2(acc) (== exp(sim/tau)), reduce rows & cols ----
    float rp[8][4] = {{0.f}};  // [fm][reg] partial row sums
    float cp[4]    = {0.f};    // [fn]      partial col sums

    if (!diag) {
        #pragma unroll
        for (int fm = 0; fm < 8; ++fm)
            #pragma unroll
            for (int fn = 0; fn < 4; ++fn) {
                const floatx4 a = acc[fm][fn];
                #pragma unroll
                for (int q = 0; q < 4; ++q) {
                    const float e = __builtin_amdgcn_exp2f(a[q]);
                    rp[fm][q] += e;
                    cp[fn]    += e;
                }
            }
    } else {
        #pragma unroll
        for (int fm = 0; fm < 8; ++fm)
            #pragma unroll
            for (int fn = 0; fn < 4; ++fn) {
                const floatx4 a = acc[fm][fn];
                const int cl = wn * 64 + fn * 16 + m15;
                #pragma unroll
                for (int q = 0; q < 4; ++q) {
                    const int rl = wm * 128 + fm * 16 + g * 4 + q;
                    float e = __builtin_amdgcn_exp2f(a[q]);
                    if (cl <= rl) e = 0.f;   // strictly-upper only
                    rp[fm][q] += e;
                    cp[fn]    += e;
                }
            }
    }

    // row sums: 16-lane DPP reduction (VALU pipe); total lands in m15==0
    #pragma unroll
    for (int fm = 0; fm < 8; ++fm)
        #pragma unroll
        for (int q = 0; q < 4; ++q) {
            float v = rp[fm][q];
            DPP_ROW_SHL_ADD(v, 0x101);   // row_shl:1
            DPP_ROW_SHL_ADD(v, 0x102);   // row_shl:2
            DPP_ROW_SHL_ADD(v, 0x104);   // row_shl:4
            DPP_ROW_SHL_ADD(v, 0x108);   // row_shl:8
            rp[fm][q] = v;
        }
    if (m15 == 0) {
        #pragma unroll
        for (int fm = 0; fm < 8; ++fm)
            #pragma unroll
            for (int q = 0; q < 4; ++q)
                atomicAdd(&rs[wm * 128 + fm * 16 + g * 4 + q], rp[fm][q]);
    }

    // col sums: reduce across quads (xor 16/32 crosses DPP rows -> keep shfl)
    #pragma unroll
    for (int mask = 16; mask < 64; mask <<= 1)
        #pragma unroll
        for (int fn = 0; fn < 4; ++fn)
            cp[fn] += __shfl_xor(cp[fn], mask);
    if (g == 0) {
        #pragma unroll
        for (int fn = 0; fn < 4; ++fn)
            atomicAdd(&cs[wn * 64 + fn * 16 + m15], cp[fn]);
    }

    __syncthreads();
    if (tid < TM) {
        atomicAdd(&rowsum[(size_t)bi * TM + tid], rs[tid]);
        atomicAdd(&rowsum[(size_t)bj * TM + tid], cs[tid]);
    }
}

// ---------------------------------------------------------------------------
// Kernel 3: loss = mean( log(rowsum_i) - 2*pos_i ), 16 blocks + atomic.
// out[0] zeroed by normalize_kernel (stream-ordered).
// ---------------------------------------------------------------------------
__global__ __launch_bounds__(1024) void finalize_kernel(
    const float* __restrict__ rowsum, const float* __restrict__ pos,
    float* __restrict__ out)
{
    const int i = threadIdx.x + blockIdx.x * 1024;
    float s = logf(rowsum[i]) - 2.0f * pos[i];
    #pragma unroll
    for (int off = 32; off; off >>= 1) s += __shfl_down(s, off);
    __shared__ float sh[16];
    const int lt = threadIdx.x;
    if ((lt & 63) == 0) sh[lt >> 6] = s;
    __syncthreads();
    if (lt == 0) {
        float tot = 0.f;
        #pragma unroll
        for (int w = 0; w < 16; ++w) tot += sh[w];
        atomicAdd(out, tot / (float)N2);
    }
}

// ---------------------------------------------------------------------------
extern "C" void kernel_launch(void* const* d_in, const int* in_sizes, int n_in,
                              void* d_out, int out_size, void* d_ws, size_t ws_size,
                              hipStream_t stream)
{
    const float* x = (const float*)d_in[0];
    const float* y = (const float*)d_in[1];

    // workspace: Z bf16 [16384*256] (8 MB) | rowsum f32 [16384] | pos f32 [16384]
    __hip_bfloat16* Z = (__hip_bfloat16*)d_ws;
    float* rowsum = (float*)((char*)d_ws + (size_t)N2 * HDIM * sizeof(__hip_bfloat16));
    float* pos    = rowsum + N2;

    normalize_kernel<<<NROWS / 4, 256, 0, stream>>>(x, y, Z, pos, rowsum, (float*)d_out);
    simgemm_kernel<<<NBLK, 512, 0, stream>>>(Z, rowsum);
    finalize_kernel<<<N2 / 1024, 1024, 0, stream>>>(rowsum, pos, (float*)d_out);
}

// Round 8
// 151.577 us; speedup vs baseline: 1.0967x; 1.0151x over previous
//
#include <hip/hip_runtime.h>
#include <hip/hip_bf16.h>
#include <math.h>

// Problem constants (fixed by reference setup_inputs)
constexpr int NROWS = 8192;   // B
constexpr int HDIM  = 256;    // H (= K of the GEMM)
constexpr int N2    = 16384;  // 2*B rows of Z
constexpr int TM    = 256;    // tile M = tile N; 16 waves of 64x64 out each
constexpr int BK    = 32;     // K chunk staged per round (8 chunks)
constexpr int NCHUNK = HDIM / BK;     // 8
constexpr int PIECE = TM * BK;        // 8192 elems = 16 KB per piece
constexpr int NTILE = N2 / TM;        // 64 tile-rows
constexpr int NBLK  = NTILE * (NTILE + 1) / 2;  // 2080 upper-tri tiles

// sqrt(2 * log2(e)): Z pre-scaled so Zs_i.Zs_j = 2*log2(e)*cos and
// exp2(acc) == exp(sim/tau), tau = 0.5
constexpr float PRESCALE = 1.69864357f;

typedef __attribute__((ext_vector_type(4))) float floatx4;
typedef __attribute__((ext_vector_type(8))) short shortx8; // 8 bf16 = 4 VGPRs

__device__ __forceinline__ void async_copy16(const void* gptr, void* lptr) {
    __builtin_amdgcn_global_load_lds(
        (const __attribute__((address_space(1))) unsigned int*)gptr,
        (__attribute__((address_space(3))) unsigned int*)lptr, 16, 0, 0);
}

// s_waitcnt immediates (gfx9: vm[3:0], exp[6:4], lgkm[11:8], vm-hi[15:14])
#define WAIT_VM2()   __builtin_amdgcn_s_waitcnt(0x0F72)  // vmcnt(2)
#define WAIT_VM0()   __builtin_amdgcn_s_waitcnt(0x0F70)  // vmcnt(0)
#define MEMFENCE()   __asm__ __volatile__("" ::: "memory")
#define RAW_BARRIER() do { MEMFENCE(); __builtin_amdgcn_s_barrier(); MEMFENCE(); } while (0)

// DPP row_shl add: VALU pipe, not DS (R9: -18us vs ds_bpermute shuffles).
#define DPP_ROW_SHL_ADD(v, CTRL) do {                                        \
    union { float f; int i; } _u, _r; _u.f = (v);                            \
    _r.i = __builtin_amdgcn_update_dpp(0, _u.i, (CTRL), 0xF, 0xF, true);     \
    (v) += _r.f; } while (0)

// ---------------------------------------------------------------------------
// Kernel 1: wave-per-row L2-normalize -> bf16 Z (pre-scaled); pos = cos(x,y).
// Also zeroes rowsum and out (stream-ordered before consumers).
// ---------------------------------------------------------------------------
__global__ __launch_bounds__(256) void normalize_kernel(
    const float* __restrict__ x, const float* __restrict__ y,
    __hip_bfloat16* __restrict__ Z, float* __restrict__ pos,
    float* __restrict__ rowsum, float* __restrict__ out)
{
    const int wave = threadIdx.x >> 6, lane = threadIdx.x & 63;
    const int row  = blockIdx.x * 4 + wave;           // grid 2048 -> 8192 rows

    const float4 xv = ((const float4*)x)[row * 64 + lane];
    const float4 yv = ((const float4*)y)[row * 64 + lane];

    float sx  = xv.x*xv.x + xv.y*xv.y + xv.z*xv.z + xv.w*xv.w;
    float sy  = yv.x*yv.x + yv.y*yv.y + yv.z*yv.z + yv.w*yv.w;
    float sxy = xv.x*yv.x + xv.y*yv.y + xv.z*yv.z + xv.w*yv.w;
    #pragma unroll
    for (int m = 1; m < 64; m <<= 1) {
        sx  += __shfl_xor(sx,  m);
        sy  += __shfl_xor(sy,  m);
        sxy += __shfl_xor(sxy, m);
    }
    const float rxn = rsqrtf(sx), ryn = rsqrtf(sy);
    const float rx = rxn * PRESCALE, ry = ryn * PRESCALE;

    union { ushort4 u; __hip_bfloat16 h[4]; } zx, zy;
    zx.h[0] = __float2bfloat16(xv.x * rx); zx.h[1] = __float2bfloat16(xv.y * rx);
    zx.h[2] = __float2bfloat16(xv.z * rx); zx.h[3] = __float2bfloat16(xv.w * rx);
    zy.h[0] = __float2bfloat16(yv.x * ry); zy.h[1] = __float2bfloat16(yv.y * ry);
    zy.h[2] = __float2bfloat16(yv.z * ry); zy.h[3] = __float2bfloat16(yv.w * ry);
    ((ushort4*)Z)[row * 64 + lane]             = zx.u;
    ((ushort4*)Z)[(row + NROWS) * 64 + lane]   = zy.u;

    if (lane == 0) {
        const float p = sxy * rxn * ryn;
        pos[row]         = p;
        pos[row + NROWS] = p;
    }
    const int gt = blockIdx.x * 256 + threadIdx.x;
    if (gt < N2) rowsum[gt] = 0.f;
    if (gt == 0) out[0] = 0.f;
}

// ---------------------------------------------------------------------------
// Kernel 2: upper-triangle tiled Z·Z^T, fused exp2 + row/col sums.
// R16: 256^2 tile, 16 WAVES (1024 thr) x 64x64 out each; acc[4][4] = 64
// AGPR/wave -> combined regs <= 128 via __launch_bounds__(1024,4) -> 4
// waves/SIMD. Diagnosis after R10-R15 (8 schedule variants all 24-30%
// MfmaUtil; MFMA pipe 30%, LDS ~16%, HBM 4.6%, real VALU ~3%, conflicts 0
// — nothing saturated): the kernel is LATENCY-bound with only 2 lockstep
// waves/SIMD (244 combined regs capped occupancy); every per-wave stall
// (ds return, barrier spread, vm gate, exp2) idles the SIMD. 4 waves/SIMD
// doubles issue diversity at the stall points. Schedule = R10's proven
// 3-buffer 1-barrier-per-chunk (WAR story below), staging XOR swizzle and
// fragment sw swizzle carried verbatim (R6-validated, 0 conflicts).
//   body s: if s+1<8 {STAGE(s+1)->buf (s+1)%3; vmcnt(2)} else vmcnt(0);
//           BARRIER (chunk-s landed for all); ds_read buf s%3; 16 MFMA.
// WAR: STAGE(s+1) writes buf (s+1)%3, last read in body s-2; the issuing
// wave passed barrier(s-1), which all waves reached only after their
// body-(s-2) ds_reads retired (compiler lgkm gates precede the consuming
// MFMAs; DS retires in-order). RAW: per-wave vmcnt gate covers chunk-s's
// own 2 copies; barrier collectivizes. No device-scope fences (R5). No
// direct-from-global frags (R7).
// Staging: wave w covers rows [w*16, w*16+16) of A and of B: 1 copy each
// per chunk (lane l -> row w*16+(l>>2), lds slot l&3, source slot
// (l&3)^((l>>3)&3) — same per-16-row-band pattern as before).
// ---------------------------------------------------------------------------
__global__ __launch_bounds__(1024, 4) void simgemm_kernel(
    const __hip_bfloat16* __restrict__ Z, float* __restrict__ rowsum)
{
    // ---- XCD-local block -> (bi,bj) mapping (bijection onto upper tri) ----
    // 2080 = 8 XCDs x 260; per XCD: 36 diag-group tiles + 7 off-diag halves(4x8)
    const int b = blockIdx.x;
    const int k = b & 7;        // XCD under round-robin dispatch heuristic
    const int m = b >> 3;       // 0..259 local rank within XCD
    int bi, bj;
    if (m < 36) {
        // diagonal group k: 8x8 upper triangle, cum(t) = t*(17-t)/2
        int ti = (int)((17.0f - sqrtf(289.0f - 8.0f * (float)m)) * 0.5f);
        if (m < ti * (17 - ti) / 2) ti--;
        else if (m >= (ti + 1) * (16 - ti) / 2) ti++;
        const int tj = ti + (m - ti * (17 - ti) / 2);
        bi = k * 8 + ti;
        bj = k * 8 + tj;
    } else {
        const int m2 = m - 36;           // 0..223
        const int hh = m2 >> 5;          // 0..6  (which of my 7 halves)
        const int r  = m2 & 31;          // 0..31 within half (4x8 tiles)
        const int h  = hh * 8 + k;       // 0..55 global half index
        const int q  = h >> 1;           // 0..27 off-diag group pair
        const int sub = h & 1;
        // pair q -> (gi,gj), gi<gj<8, cum(gi) = gi*(15-gi)/2
        int gi = 0;
        #pragma unroll
        for (int t = 6; t > 0; --t)
            if (q >= t * (15 - t) / 2) { gi = t; break; }
        const int gj = gi + 1 + (q - gi * (15 - gi) / 2);
        bi = gi * 8 + sub * 4 + (r >> 3);
        bj = gj * 8 + (r & 7);
    }
    const bool diag = (bi == bj);

    // LDS: 3 buffers x (tA 16KB + tB 16KB) = 96KB, + rs/cs 2KB = 98KB
    __shared__ alignas(16) __hip_bfloat16 tiles[6 * PIECE];  // 96 KB
    __shared__ float rs[TM];
    __shared__ float cs[TM];
    __hip_bfloat16* tA = tiles;                  // + buf * 2*PIECE
    __hip_bfloat16* tB = tiles + PIECE;          // + buf * 2*PIECE

    const int tid  = threadIdx.x;
    const int wave = tid >> 6;            // 0..15
    const int lane = tid & 63;
    const int wm   = wave & 3;            // wave row band (0..3): rows wm*64..+64
    const int wn   = wave >> 2;           // wave col band (0..3): cols wn*64..+64
    const int g    = lane >> 4;           // quad  (0..3)
    const int m15  = lane & 15;

    if (tid < TM) { rs[tid] = 0.f; cs[tid] = 0.f; }

    // ---- staging addresses (computed once) ----
    // wave w stages 16 rows of A and 16 rows of B per chunk (1 copy each).
    // lane l covers LDS row w*16 + (l>>2), lds 16B-slot l&3; swizzled
    // source slot = (l&3) ^ ((l>>3)&3)   [R6-validated, 0 conflicts]
    const int st_r0  = wave * 16 + (lane >> 2);
    const int st_c   = (lane & 3) ^ ((lane >> 3) & 3);     // source chunk
    const __hip_bfloat16* gA0 = Z + (size_t)(bi * TM + st_r0) * HDIM + st_c * 8;
    const __hip_bfloat16* gB0 = Z + (size_t)(bj * TM + st_r0) * HDIM + st_c * 8;
    // wave-uniform LDS bases (lane scatter is +l*16B)
    __hip_bfloat16* lA0 = tA + (wave * 16) * BK;
    __hip_bfloat16* lB0 = tB + (wave * 16) * BK;

    // ---- fragment read addresses (all f-offsets immediates) ----
    const int sw = g ^ ((m15 >> 1) & 3);
    const __hip_bfloat16* rA = tA + (wm * 64 + m15) * BK + sw * 8;
    const __hip_bfloat16* rB = tB + (wn * 64 + m15) * BK + sw * 8;

    floatx4 acc[4][4] = {};

    // chunk ck -> buffer ck%3; global offset ck*BK folds where possible
    #define STAGE(ck)  do {                                                  \
        const int _o = ((ck) % 3) * 2 * PIECE;                               \
        async_copy16(gA0 + (ck) * BK, lA0 + _o);                             \
        async_copy16(gB0 + (ck) * BK, lB0 + _o);                             \
    } while (0)

    STAGE(0);   // prologue (2 loads in flight entering body 0)

    #pragma unroll
    for (int s = 0; s < NCHUNK; ++s) {
        if (s + 1 < NCHUNK) { STAGE(s + 1); WAIT_VM2(); }
        else                { WAIT_VM0(); }
        RAW_BARRIER();   // all waves' chunk-s loads landed in buf s%3

        const int bo = (s % 3) * 2 * PIECE;
        shortx8 af[4], bfr[4];
        #pragma unroll
        for (int f = 0; f < 4; ++f) {
            af[f]  = *(const shortx8*)(rA + bo + f * 16 * BK);
            bfr[f] = *(const shortx8*)(rB + bo + f * 16 * BK);
        }
        __builtin_amdgcn_s_setprio(1);
        #pragma unroll
        for (int fm = 0; fm < 4; ++fm)
            #pragma unroll
            for (int fn = 0; fn < 4; ++fn)
                acc[fm][fn] = __builtin_amdgcn_mfma_f32_16x16x32_bf16(
                    af[fm], bfr[fn], acc[fm][fn], 0, 0, 0);
        __builtin_amdgcn_s_setprio(0);
        // no 2nd barrier / lgkm drain: WAR argument in header comment
    }
    #undef STAGE

    // ---- epilogue: e = exp2(acc) (== exp(sim/tau)), reduce rows & cols ----
    float rp[4][4] = {{0.f}};  // [fm][reg] partial row sums
    float cp[4]    = {0.f};    // [fn]      partial col sums

    if (!diag) {
        #pragma unroll
        for (int fm = 0; fm < 4; ++fm)
            #pragma unroll
            for (int fn = 0; fn < 4; ++fn) {
                const floatx4 a = acc[fm][fn];
                #pragma unroll
                for (int q = 0; q < 4; ++q) {
                    const float e = __builtin_amdgcn_exp2f(a[q]);
                    rp[fm][q] += e;
                    cp[fn]    += e;
                }
            }
    } else {
        #pragma unroll
        for (int fm = 0; fm < 4; ++fm)
            #pragma unroll
            for (int fn = 0; fn < 4; ++fn) {
                const floatx4 a = acc[fm][fn];
                const int cl = wn * 64 + fn * 16 + m15;
                #pragma unroll
                for (int q = 0; q < 4; ++q) {
                    const int rl = wm * 64 + fm * 16 + g * 4 + q;
                    float e = __builtin_amdgcn_exp2f(a[q]);
                    if (cl <= rl) e = 0.f;   // strictly-upper only
                    rp[fm][q] += e;
                    cp[fn]    += e;
                }
            }
    }

    // row sums: 16-lane DPP reduction (VALU pipe); total lands in m15==0
    #pragma unroll
    for (int fm = 0; fm < 4; ++fm)
        #pragma unroll
        for (int q = 0; q < 4; ++q) {
            float v = rp[fm][q];
            DPP_ROW_SHL_ADD(v, 0x101);   // row_shl:1
            DPP_ROW_SHL_ADD(v, 0x102);   // row_shl:2
            DPP_ROW_SHL_ADD(v, 0x104);   // row_shl:4
            DPP_ROW_SHL_ADD(v, 0x108);   // row_shl:8
            rp[fm][q] = v;
        }
    if (m15 == 0) {
        #pragma unroll
        for (int fm = 0; fm < 4; ++fm)
            #pragma unroll
            for (int q = 0; q < 4; ++q)
                atomicAdd(&rs[wm * 64 + fm * 16 + g * 4 + q], rp[fm][q]);
    }

    // col sums: reduce across quads (xor 16/32 crosses DPP rows -> keep shfl)
    #pragma unroll
    for (int mask = 16; mask < 64; mask <<= 1)
        #pragma unroll
        for (int fn = 0; fn < 4; ++fn)
            cp[fn] += __shfl_xor(cp[fn], mask);
    if (g == 0) {
        #pragma unroll
        for (int fn = 0; fn < 4; ++fn)
            atomicAdd(&cs[wn * 64 + fn * 16 + m15], cp[fn]);
    }

    __syncthreads();
    if (tid < TM) {
        atomicAdd(&rowsum[(size_t)bi * TM + tid], rs[tid]);
        atomicAdd(&rowsum[(size_t)bj * TM + tid], cs[tid]);
    }
}

// ---------------------------------------------------------------------------
// Kernel 3: loss = mean( log(rowsum_i) - 2*pos_i ), 16 blocks + atomic.
// out[0] zeroed by normalize_kernel (stream-ordered).
// ---------------------------------------------------------------------------
__global__ __launch_bounds__(1024) void finalize_kernel(
    const float* __restrict__ rowsum, const float* __restrict__ pos,
    float* __restrict__ out)
{
    const int i = threadIdx.x + blockIdx.x * 1024;
    float s = logf(rowsum[i]) - 2.0f * pos[i];
    #pragma unroll
    for (int off = 32; off; off >>= 1) s += __shfl_down(s, off);
    __shared__ float sh[16];
    const int lt = threadIdx.x;
    if ((lt & 63) == 0) sh[lt >> 6] = s;
    __syncthreads();
    if (lt == 0) {
        float tot = 0.f;
        #pragma unroll
        for (int w = 0; w < 16; ++w) tot += sh[w];
        atomicAdd(out, tot / (float)N2);
    }
}

// ---------------------------------------------------------------------------
extern "C" void kernel_launch(void* const* d_in, const int* in_sizes, int n_in,
                              void* d_out, int out_size, void* d_ws, size_t ws_size,
                              hipStream_t stream)
{
    const float* x = (const float*)d_in[0];
    const float* y = (const float*)d_in[1];

    // workspace: Z bf16 [16384*256] (8 MB) | rowsum f32 [16384] | pos f32 [16384]
    __hip_bfloat16* Z = (__hip_bfloat16*)d_ws;
    float* rowsum = (float*)((char*)d_ws + (size_t)N2 * HDIM * sizeof(__hip_bfloat16));
    float* pos    = rowsum + N2;

    normalize_kernel<<<NROWS / 4, 256, 0, stream>>>(x, y, Z, pos, rowsum, (float*)d_out);
    simgemm_kernel<<<NBLK, 1024, 0, stream>>>(Z, rowsum);
    finalize_kernel<<<N2 / 1024, 1024, 0, stream>>>(rowsum, pos, (float*)d_out);
}